// Round 13
// baseline (132.726 us; speedup 1.0000x reference)
//
#include <hip/hip_runtime.h>
#include <hip/hip_fp16.h>

#define NP    128   // planets per batch
#define NH    64    // hidden dim
#define RST   18    // epilogue LDS row stride in floats
#define ITERS 8     // batches per wave
#define WPB   4     // waves per block

typedef __attribute__((ext_vector_type(8))) _Float16 f16x8;   // K32 MFMA A/B operand
typedef __attribute__((ext_vector_type(4))) _Float16 f16x4;   // K16 MFMA A/B operand
typedef __attribute__((ext_vector_type(2))) __fp16  hf16x2;   // cvt_pkrtz return type
typedef __attribute__((ext_vector_type(4))) float f32x4;

union FragK16 { f16x4 v; unsigned int u[2]; };
union FragK32 { f16x8 v; unsigned int u[4]; };

__device__ __forceinline__ unsigned int pack_pkrtz(float a, float b) {
    hf16x2 t = __builtin_amdgcn_cvt_pkrtz(a, b);
    return __builtin_bit_cast(unsigned int, t);
}

// packed f16 relu (v_pk_max_f16). relu(rtz(x)) == rtz(relu(x)).
__device__ __forceinline__ unsigned int relu2_pk(unsigned int u) {
    hf16x2 h = __builtin_bit_cast(hf16x2, u);
    h = __builtin_elementwise_max(h, (hf16x2)(__fp16)0.f);
    return __builtin_bit_cast(unsigned int, h);
}

// 4 independent waves/block, ITERS batches each, fully register-resident.
// sigma h-permutation (R12, validated): layer2 K32 B-operand = concatenation of
// layer1 K16 C-outputs; W2 loaded sigma-permuted at setup.
// R13: explicit 2-slab ILP interleave + next-batch pxy prefetch (ping-pong).
// Same-wave DS is in-order (validated R10-R12) -> no barriers anywhere.
__global__ void __launch_bounds__(256, 2) gnn_wave(
    const float* __restrict__ planet_xy,  // [B][P][2]
    const float* __restrict__ planet_m,   // [P]
    const float* __restrict__ ast_xy,     // [B][2]
    const float* __restrict__ W1,         // [4][64]
    const float* __restrict__ b1,         // [64]
    const float* __restrict__ W2,         // [64][64]
    const float* __restrict__ b2,         // [64]
    float* __restrict__ out,              // [B][64]
    int B)
{
    __shared__ float rsum[WPB][64 * RST];

    const int tid  = threadIdx.x;
    const int wv   = tid >> 6;
    const int lane = tid & 63;
    const int q    = lane >> 4;
    const int lm   = lane & 15;
    const bool q0  = (q == 0);
    const bool q1  = (q == 1);

    // ---- layer1 A-frags (16x16x16), b1 folded as constant-1 feature k=4 ----
    FragK16 w1f[4];
    #pragma unroll
    for (int mt = 0; mt < 4; mt++) {
        const int m = 16 * mt + lm;
        float wa = W1[0 * NH + m], wb = W1[1 * NH + m];
        float wc = W1[2 * NH + m], wd = W1[3 * NH + m];
        float be = b1[m];
        w1f[mt].u[0] = q0 ? pack_pkrtz(wa, wb) : (q1 ? pack_pkrtz(be, 0.f) : 0u);
        w1f[mt].u[1] = q0 ? pack_pkrtz(wc, wd) : 0u;
    }

    // ---- layer2 A-frags (16x16x32), sigma-permuted W2^T (R12, validated) ----
    FragK32 w2a[4][2];   // [np][kk]
    #pragma unroll
    for (int np = 0; np < 4; np++)
        #pragma unroll
        for (int kk = 0; kk < 2; kk++) {
            const int n = 16 * np + lm;
            const int k0 = 32 * kk + 4 * q;
            const int k1 = 32 * kk + 16 + 4 * q;
            w2a[np][kk].u[0] = pack_pkrtz(W2[(k0 + 0) * NH + n], W2[(k0 + 1) * NH + n]);
            w2a[np][kk].u[1] = pack_pkrtz(W2[(k0 + 2) * NH + n], W2[(k0 + 3) * NH + n]);
            w2a[np][kk].u[2] = pack_pkrtz(W2[(k1 + 0) * NH + n], W2[(k1 + 1) * NH + n]);
            w2a[np][kk].u[3] = pack_pkrtz(W2[(k1 + 2) * NH + n], W2[(k1 + 3) * NH + n]);
        }

    // b2 as layer2 C-init: rows n = 16np+4q+r
    f32x4 b2f[4];
    #pragma unroll
    for (int np = 0; np < 4; np++)
        b2f[np] = *(const f32x4*)&b2[16 * np + 4 * q];

    float pmv[8];
    #pragma unroll
    for (int i = 0; i < 8; i++)
        pmv[i] = planet_m[16 * i + lm];

    const unsigned int bf0_const = q1 ? pack_pkrtz(1.f, 0.f) : 0u;
    const f32x4 zf = (f32x4){0.f, 0.f, 0.f, 0.f};

    const int b0 = (blockIdx.x * WPB + wv) * ITERS;
    const int bMax = B - 1;

    float2 pxyA[8], pxyB[8];
    float2 axyA, axyB;
    {
        const int bl = (b0 <= bMax) ? b0 : bMax;
        #pragma unroll
        for (int i = 0; i < 8; i++)
            pxyA[i] = *(const float2*)&planet_xy[((size_t)bl * NP + 16 * i + lm) * 2];
        axyA = *(const float2*)&ast_xy[2 * bl];
    }

// One batch: prefetch next into PNXT/AXYN, compute slabs in ILP pairs, reduce.
#define GNN_BODY(PCUR, PNXT, AXY, AXYN, BB, BN)                                     \
    {                                                                               \
        const int bn_ = ((BN) <= bMax) ? (BN) : bMax;                               \
        _Pragma("unroll")                                                           \
        for (int i = 0; i < 8; i++)                                                 \
            PNXT[i] = *(const float2*)&planet_xy[((size_t)bn_ * NP + 16 * i + lm) * 2]; \
        AXYN = *(const float2*)&ast_xy[2 * bn_];                                    \
        f32x4 sums[4];                                                              \
        _Pragma("unroll")                                                           \
        for (int np = 0; np < 4; np++) sums[np] = zf;                               \
        _Pragma("unroll")                                                           \
        for (int mi = 0; mi < 8; mi += 2) {                                         \
            float dxa = PCUR[mi].x - AXY.x,     dya = PCUR[mi].y - AXY.y;           \
            float dxb = PCUR[mi + 1].x - AXY.x, dyb = PCUR[mi + 1].y - AXY.y;       \
            float inva = __builtin_amdgcn_rsqf(fmaf(dxa, dxa, fmaf(dya, dya, 1e-6f))); \
            float invb = __builtin_amdgcn_rsqf(fmaf(dxb, dxb, fmaf(dyb, dyb, 1e-6f))); \
            FragK16 bfa, bfb;                                                       \
            bfa.u[0] = q0 ? pack_pkrtz(dxa, dya)          : bf0_const;              \
            bfa.u[1] = q0 ? pack_pkrtz(inva, pmv[mi])     : 0u;                     \
            bfb.u[0] = q0 ? pack_pkrtz(dxb, dyb)          : bf0_const;              \
            bfb.u[1] = q0 ? pack_pkrtz(invb, pmv[mi + 1]) : 0u;                     \
            FragK32 hBa[2], hBb[2];                                                 \
            _Pragma("unroll")                                                       \
            for (int mt = 0; mt < 4; mt++) {                                        \
                f32x4 ca = __builtin_amdgcn_mfma_f32_16x16x16f16(w1f[mt].v, bfa.v, zf, 0, 0, 0); \
                f32x4 cb = __builtin_amdgcn_mfma_f32_16x16x16f16(w1f[mt].v, bfb.v, zf, 0, 0, 0); \
                hBa[mt >> 1].u[(mt & 1) * 2 + 0] = relu2_pk(pack_pkrtz(ca[0], ca[1])); \
                hBa[mt >> 1].u[(mt & 1) * 2 + 1] = relu2_pk(pack_pkrtz(ca[2], ca[3])); \
                hBb[mt >> 1].u[(mt & 1) * 2 + 0] = relu2_pk(pack_pkrtz(cb[0], cb[1])); \
                hBb[mt >> 1].u[(mt & 1) * 2 + 1] = relu2_pk(pack_pkrtz(cb[2], cb[3])); \
            }                                                                       \
            _Pragma("unroll")                                                       \
            for (int np = 0; np < 4; np++) {                                        \
                f32x4 acca = __builtin_amdgcn_mfma_f32_16x16x32_f16(w2a[np][0].v, hBa[0].v, b2f[np], 0, 0, 0); \
                f32x4 accb = __builtin_amdgcn_mfma_f32_16x16x32_f16(w2a[np][0].v, hBb[0].v, b2f[np], 0, 0, 0); \
                acca = __builtin_amdgcn_mfma_f32_16x16x32_f16(w2a[np][1].v, hBa[1].v, acca, 0, 0, 0); \
                accb = __builtin_amdgcn_mfma_f32_16x16x32_f16(w2a[np][1].v, hBb[1].v, accb, 0, 0, 0); \
                sums[np] += __builtin_elementwise_max(acca, zf);                    \
                sums[np] += __builtin_elementwise_max(accb, zf);                    \
            }                                                                       \
        }                                                                           \
        _Pragma("unroll")                                                           \
        for (int np = 0; np < 4; np++)                                              \
            _Pragma("unroll")                                                       \
            for (int r = 0; r < 4; r++)                                             \
                rsum[wv][(16 * np + 4 * q + r) * RST + lm] = sums[np][r];           \
        float tot = 0.f;                                                            \
        _Pragma("unroll")                                                           \
        for (int i = 0; i < 8; i++) {                                               \
            float2 v2 = *(const float2*)&rsum[wv][lane * RST + 2 * i];              \
            tot += v2.x + v2.y;                                                     \
        }                                                                           \
        if ((BB) <= bMax) out[(size_t)(BB) * NH + lane] = tot;                      \
    }

    for (int it2 = 0; it2 < ITERS; it2 += 2) {
        const int b = b0 + it2;
        GNN_BODY(pxyA, pxyB, axyA, axyB, b, b + 1);
        GNN_BODY(pxyB, pxyA, axyB, axyA, b + 1, b + 2);
    }
#undef GNN_BODY
}

extern "C" void kernel_launch(void* const* d_in, const int* in_sizes, int n_in,
                              void* d_out, int out_size, void* d_ws, size_t ws_size,
                              hipStream_t stream) {
    const float* planet_xy = (const float*)d_in[0];
    const float* planet_m  = (const float*)d_in[1];
    const float* ast_xy    = (const float*)d_in[2];
    const float* W1        = (const float*)d_in[3];
    const float* b1        = (const float*)d_in[4];
    const float* W2        = (const float*)d_in[5];
    const float* b2        = (const float*)d_in[6];
    float* outp            = (float*)d_out;

    const int B = in_sizes[2] / 2;   // ast_xy is [B][2]
    const int batches_per_block = WPB * ITERS;
    const int grid = (B + batches_per_block - 1) / batches_per_block;

    gnn_wave<<<grid, 256, 0, stream>>>(planet_xy, planet_m, ast_xy, W1, b1, W2, b2, outp, B);
}